// Round 18
// baseline (230.176 us; speedup 1.0000x reference)
//
#include <hip/hip_runtime.h>

#define T_STEPS 301
#define IN_DIM  40
#define LOG2E   1.44269504088896340736f

typedef __attribute__((ext_vector_type(8))) _Float16 f16x8;
typedef __attribute__((ext_vector_type(4))) float f32x4;
typedef unsigned short ushort_t;
typedef unsigned int uint_t;

union u16cv { _Float16 hf; ushort_t u; };

#define MFMA16(A, B, C) __builtin_amdgcn_mfma_f32_16x16x32_f16((A), (B), (C), 0, 0, 0)
#define SGB __builtin_amdgcn_sched_group_barrier

__device__ __forceinline__ f16x8 cvt8h(const float4 a, const float4 b) {
  f16x8 r;
  r[0] = (_Float16)a.x; r[1] = (_Float16)a.y; r[2] = (_Float16)a.z; r[3] = (_Float16)a.w;
  r[4] = (_Float16)b.x; r[5] = (_Float16)b.y; r[6] = (_Float16)b.z; r[7] = (_Float16)b.w;
  return r;
}

// z pre-scaled by log2e (2*log2e for g-gate) -> exp2-based activations.
__device__ __forceinline__ float lstm_act(float zi, float zf, float zg, float zo, float& cc) {
  const float ig = __builtin_amdgcn_rcpf(1.0f + __builtin_amdgcn_exp2f(-zi));
  const float fg = __builtin_amdgcn_rcpf(1.0f + __builtin_amdgcn_exp2f(-zf));
  const float gg = 1.0f - 2.0f * __builtin_amdgcn_rcpf(1.0f + __builtin_amdgcn_exp2f(zg));
  const float og = __builtin_amdgcn_rcpf(1.0f + __builtin_amdgcn_exp2f(-zo));
  cc = fg * cc + ig * gg;
  const float tc = 1.0f - 2.0f * __builtin_amdgcn_rcpf(1.0f + __builtin_amdgcn_exp2f(cc * (2.0f * LOG2E)));
  return og * tc;
}

// R18 = R14 base (zero-waste M=16, z/zn ping-pong, 256 blocks x 256 thr) with:
//  (a) x kept as PRE-CONVERTED f16 frags across the barrier (cvt done one step
//      early from f32 prefetch regs) -> step T's 8 xproj MFMAs depend only on
//      loop-carried registers, no VALU prerequisites;
//  (b) sched_group_barrier bundle that is now satisfiable from slot 0:
//      2 DS_READ -> 8 MFMA (rec) -> 8 x {2 MFMA (xproj), 12 VALU (act)}.
//  Pipeline regs entering step T: xfA/xfB = f16(x[T+1]); pxR = f32 x[T+2].
//  Step T: rec(T); xproj(T+1) from xfA/xfB; cvt pxR -> xfA' (=x[T+2]);
//  prefetch x[T+3] -> pxR'; act(T); write h; barrier.
__global__ __launch_bounds__(256, 1)
void lstm_sh(const float* __restrict__ x, const float* __restrict__ w_ih,
             const float* __restrict__ w_hh, const float* __restrict__ b_ih,
             const float* __restrict__ b_hh, const float* __restrict__ w_clf,
             const float* __restrict__ b_clf, float* __restrict__ out) {
  extern __shared__ char smem[];
  float*    wclf  = (float*)smem;                       // [301][64], 77056 B
  ushort_t* hflat = (ushort_t*)(smem + 77056);          // [2][16][64], 4096 B
  float*    red   = (float*)(smem + 77056 + 4096);      // [4][16], 256 B

  const int tid = threadIdx.x;
  const int l   = tid & 63, w = tid >> 6;
  const int c15 = l & 15, g16 = l >> 4;
  const int n   = w * 16 + c15;
  const int b0  = blockIdx.x * 16;
  const float gsc[4] = {LOG2E, LOG2E, 2.0f * LOG2E, LOG2E};

  for (int i = tid; i < (T_STEPS * 64) / 4; i += 256)
    ((float4*)wclf)[i] = ((const float4*)w_clf)[i];
  for (int i = tid; i < 1024; i += 256) ((uint_t*)hflat)[i] = 0;

  // ---- weights in registers (fp16, prescaled); bias via k=40 channel ----
  f16x8 whh[4][2], wih[4][2];
#pragma unroll
  for (int g = 0; g < 4; ++g) {
    const float s = gsc[g];
    const float* wr = w_hh + (size_t)(g * 64 + n) * 64;
#pragma unroll
    for (int kc = 0; kc < 2; ++kc) {
      float4 v0 = *(const float4*)(wr + kc * 32 + g16 * 8);
      float4 v1 = *(const float4*)(wr + kc * 32 + g16 * 8 + 4);
      v0.x *= s; v0.y *= s; v0.z *= s; v0.w *= s;
      v1.x *= s; v1.y *= s; v1.z *= s; v1.w *= s;
      whh[g][kc] = cvt8h(v0, v1);
    }
    const float* wi = w_ih + (size_t)(g * 64 + n) * IN_DIM;
    {
      float4 v0 = *(const float4*)(wi + g16 * 8);
      float4 v1 = *(const float4*)(wi + g16 * 8 + 4);
      v0.x *= s; v0.y *= s; v0.z *= s; v0.w *= s;
      v1.x *= s; v1.y *= s; v1.z *= s; v1.w *= s;
      wih[g][0] = cvt8h(v0, v1);
    }
    {
      float4 u0 = make_float4(0, 0, 0, 0), u1 = make_float4(0, 0, 0, 0);
      if (g16 == 0) {
        u0 = *(const float4*)(wi + 32);
        u1 = *(const float4*)(wi + 36);
        u0.x *= s; u0.y *= s; u0.z *= s; u0.w *= s;
        u1.x *= s; u1.y *= s; u1.z *= s; u1.w *= s;
      } else if (g16 == 1) {
        u0.x = (b_ih[g * 64 + n] + b_hh[g * 64 + n]) * s;   // k=40 bias row
      }
      wih[g][1] = cvt8h(u0, u1);
    }
  }
  __syncthreads();

  const int akey = (c15 >> 2) << 4;
  const int ridx0 = c15 * 64 + ((0 * 32 + 8 * g16) ^ akey);
  const int ridx1 = c15 * 64 + ((1 * 32 + 8 * g16) ^ akey);
  int widx[4];
#pragma unroll
  for (int r = 0; r < 4; ++r) widx[r] = (4 * g16 + r) * 64 + (n ^ (g16 << 4));

  const float* xb = x + (size_t)(b0 + c15) * T_STEPS * IN_DIM;
  f16x8 xf1c = {};
  if (g16 == 1) xf1c[0] = (_Float16)1.0f;   // k=40 bias multiplier

  f32x4 z[4], zn[4];
  float cc[4]  = {0.f, 0.f, 0.f, 0.f};
  float acl[4] = {0.f, 0.f, 0.f, 0.f};

  // ---- prologue ----
  // xproj(t=0) directly into z (from fresh loads)
  {
    const float4 v0 = *(const float4*)(xb + g16 * 8);
    const float4 v1 = *(const float4*)(xb + g16 * 8 + 4);
    f16x8 xf0 = cvt8h(v0, v1);
    f16x8 xf1 = xf1c;
    if (g16 == 0) {
      const float4 u0 = *(const float4*)(xb + 32);
      const float4 u1 = *(const float4*)(xb + 36);
      xf1 = cvt8h(u0, u1);
    }
#pragma unroll
    for (int g = 0; g < 4; ++g) {
      f32x4 zz = {0.f, 0.f, 0.f, 0.f};
      zz = MFMA16(xf0, wih[g][0], zz);
      z[g] = MFMA16(xf1, wih[g][1], zz);
    }
  }
  // xfA/xfB = f16(x[1]); pxR = f32 x[2]
  f16x8 xfA, xfB;
  {
    const float* xp = xb + IN_DIM;
    xfA = cvt8h(*(const float4*)(xp + g16 * 8), *(const float4*)(xp + g16 * 8 + 4));
    xfB = xf1c;
    if (g16 == 0) xfB = cvt8h(*(const float4*)(xp + 32), *(const float4*)(xp + 36));
  }
  float4 px0, px1, pq0 = make_float4(0, 0, 0, 0), pq1 = make_float4(0, 0, 0, 0);
  {
    const float* xp = xb + 2 * IN_DIM;
    px0 = *(const float4*)(xp + g16 * 8);
    px1 = *(const float4*)(xp + g16 * 8 + 4);
    if (g16 == 0) {
      pq0 = *(const float4*)(xp + 32);
      pq1 = *(const float4*)(xp + 36);
    }
  }

  // STEP: rec(T) on ZC; xproj(T+1) into ZN from loop-carried xfA/xfB;
  // cvt pxR->xfA' ; prefetch x[T+3]; act(T); write h; SGB-forced interleave.
#define STEP(ZC, ZN, T, LAST)                                                     \
  {                                                                               \
    const int rb = ((T) & 1) * 1024, wb = 1024 - rb;                              \
    f16x8 a0 = *(const f16x8*)(hflat + rb + ridx0);                               \
    f16x8 a1 = *(const f16x8*)(hflat + rb + ridx1);                               \
    _Pragma("unroll")                                                             \
    for (int g = 0; g < 4; ++g) {                                                 \
      ZC[g] = MFMA16(a0, whh[g][0], ZC[g]);                                       \
      ZC[g] = MFMA16(a1, whh[g][1], ZC[g]);                                       \
    }                                                                             \
    if (!(LAST)) {                                                                \
      _Pragma("unroll")                                                           \
      for (int g = 0; g < 4; ++g) {                                               \
        f32x4 zz = {0.f, 0.f, 0.f, 0.f};                                          \
        zz = MFMA16(xfA, wih[g][0], zz);                                          \
        ZN[g] = MFMA16(xfB, wih[g][1], zz);                                       \
      }                                                                           \
      /* cvt pxR (x[T+2]) -> xfA/xfB for next step */                             \
      xfA = cvt8h(px0, px1);                                                      \
      xfB = xf1c;                                                                 \
      if (g16 == 0) xfB = cvt8h(pq0, pq1);                                        \
      /* prefetch x[T+3] */                                                       \
      const int tn = ((T) + 3 < T_STEPS) ? (T) + 3 : T_STEPS - 1;                 \
      const float* xp = xb + (size_t)tn * IN_DIM;                                 \
      px0 = *(const float4*)(xp + g16 * 8);                                       \
      px1 = *(const float4*)(xp + g16 * 8 + 4);                                   \
      if (g16 == 0) {                                                             \
        pq0 = *(const float4*)(xp + 32);                                          \
        pq1 = *(const float4*)(xp + 36);                                          \
      }                                                                           \
    }                                                                             \
    const float wc = wclf[(T) * 64 + n];                                          \
    _Pragma("unroll")                                                             \
    for (int r = 0; r < 4; ++r) {                                                 \
      const float h = lstm_act(ZC[0][r], ZC[1][r], ZC[2][r], ZC[3][r], cc[r]);    \
      acl[r] += h * wc;                                                           \
      u16cv cv; cv.hf = (_Float16)h;                                              \
      hflat[wb + widx[r]] = cv.u;                                                 \
    }                                                                             \
    /* forced order: 2 ds_read -> 8 rec MFMA -> 8 x {2 xproj MFMA, 12 VALU} */    \
    if (!(LAST)) {                                                                \
      SGB(0x100, 2, 0);                                                           \
      SGB(0x8, 8, 0);                                                             \
      _Pragma("unroll")                                                           \
      for (int q = 0; q < 8; ++q) { SGB(0x8, 2, 0); SGB(0x2, 12, 0); }            \
    }                                                                             \
    asm volatile("s_waitcnt lgkmcnt(0)\n\ts_barrier" ::: "memory");               \
  }

  for (int p = 0; p < 150; ++p) {
    const int t0 = 2 * p;
    STEP(z, zn, t0, 0)
    STEP(zn, z, t0 + 1, 0)
  }
  STEP(z, zn, 300, 1)
#undef STEP

  // ---- epilogue: reduce acl over c15 lanes, then across waves ----
#pragma unroll
  for (int m = 1; m <= 8; m <<= 1) {
#pragma unroll
    for (int r = 0; r < 4; ++r) acl[r] += __shfl_xor(acl[r], m);
  }
  if (c15 == 0) {
#pragma unroll
    for (int r = 0; r < 4; ++r) red[w * 16 + 4 * g16 + r] = acl[r];
  }
  __syncthreads();
  if (tid < 16)
    out[b0 + tid] = b_clf[0] + red[tid] + red[16 + tid] + red[32 + tid] + red[48 + tid];
}

extern "C" void kernel_launch(void* const* d_in, const int* in_sizes, int n_in,
                              void* d_out, int out_size, void* d_ws, size_t ws_size,
                              hipStream_t stream) {
  const float* x     = (const float*)d_in[0];
  const float* w_ih  = (const float*)d_in[1];
  const float* w_hh  = (const float*)d_in[2];
  const float* b_ih  = (const float*)d_in[3];
  const float* b_hh  = (const float*)d_in[4];
  const float* w_clf = (const float*)d_in[5];
  const float* b_clf = (const float*)d_in[6];
  float* out = (float*)d_out;

  const size_t shmem = 77056 + 4096 + 256;   // ~79.5 KB dynamic LDS
  (void)hipFuncSetAttribute((const void*)lstm_sh,
                            hipFuncAttributeMaxDynamicSharedMemorySize, (int)shmem);
  lstm_sh<<<256, 256, shmem, stream>>>(x, w_ih, w_hh, b_ih, b_hh, w_clf, b_clf, out);
}

// Round 19
// 229.106 us; speedup vs baseline: 1.0047x; 1.0047x over previous
//
#include <hip/hip_runtime.h>

#define T_STEPS 301
#define IN_DIM  40
#define LOG2E   1.44269504088896340736f

typedef __attribute__((ext_vector_type(8))) _Float16 f16x8;
typedef __attribute__((ext_vector_type(4))) float f32x4;
typedef unsigned short ushort_t;
typedef unsigned int uint_t;

union u16cv { _Float16 hf; ushort_t u; };

#define MFMA16(A, B, C) __builtin_amdgcn_mfma_f32_16x16x32_f16((A), (B), (C), 0, 0, 0)

__device__ __forceinline__ f16x8 cvt8h(const float4 a, const float4 b) {
  f16x8 r;
  r[0] = (_Float16)a.x; r[1] = (_Float16)a.y; r[2] = (_Float16)a.z; r[3] = (_Float16)a.w;
  r[4] = (_Float16)b.x; r[5] = (_Float16)b.y; r[6] = (_Float16)b.z; r[7] = (_Float16)b.w;
  return r;
}

// z pre-scaled by log2e (2*log2e for g-gate) -> exp2-based activations.
__device__ __forceinline__ float lstm_act(float zi, float zf, float zg, float zo, float& cc) {
  const float ig = __builtin_amdgcn_rcpf(1.0f + __builtin_amdgcn_exp2f(-zi));
  const float fg = __builtin_amdgcn_rcpf(1.0f + __builtin_amdgcn_exp2f(-zf));
  const float gg = 1.0f - 2.0f * __builtin_amdgcn_rcpf(1.0f + __builtin_amdgcn_exp2f(zg));
  const float og = __builtin_amdgcn_rcpf(1.0f + __builtin_amdgcn_exp2f(-zo));
  cc = fg * cc + ig * gg;
  const float tc = 1.0f - 2.0f * __builtin_amdgcn_rcpf(1.0f + __builtin_amdgcn_exp2f(cc * (2.0f * LOG2E)));
  return og * tc;
}

// R19: 256 blocks x 256 thr, 1 block/CU. Block = 16 batches as TWO INDEPENDENT
// groups of 8 (A, B); each group uses R6's pair-packing: M=16 rows = 8 batches
// x 2 time-offsets (row = 4*(slot>>1) + 2*toff + (slot&1)); xproj volley fills
// xw[t] (toff0 rows) and xw[t+1] (toff1 rows) once per pair; h written only to
// toff0 rows (toff1 A-rows stay zero -> xw[t+1] passes through rec untouched);
// odd step starts from shufflevector(z,[2,3,2,3]). The two groups' chains are
// INDEPENDENT -> B's read/rec fills A's stalls and the merged act region has 8
// independent trans chains for the list scheduler. Weights shared across groups.
__global__ __launch_bounds__(256, 1)
void lstm_dg(const float* __restrict__ x, const float* __restrict__ w_ih,
             const float* __restrict__ w_hh, const float* __restrict__ b_ih,
             const float* __restrict__ b_hh, const float* __restrict__ w_clf,
             const float* __restrict__ b_clf, float* __restrict__ out) {
  extern __shared__ char smem[];
  float*    wclf = (float*)smem;                        // [301][64], 77056 B
  ushort_t* hA   = (ushort_t*)(smem + 77056);           // [2][16][64], 4096 B
  ushort_t* hB   = (ushort_t*)(smem + 77056 + 4096);    // [2][16][64], 4096 B
  float*    red  = (float*)(smem + 77056 + 8192);       // [4][16], 256 B

  const int tid = threadIdx.x;
  const int l   = tid & 63, w = tid >> 6;
  const int c15 = l & 15, g16 = l >> 4;
  const int n   = w * 16 + c15;
  const int b0  = blockIdx.x * 16;
  const float gsc[4] = {LOG2E, LOG2E, 2.0f * LOG2E, LOG2E};

  for (int i = tid; i < (T_STEPS * 64) / 4; i += 256)
    ((float4*)wclf)[i] = ((const float4*)w_clf)[i];
  for (int i = tid; i < 2048; i += 256) ((uint_t*)hA)[i] = 0;   // hA+hB (contiguous)

  // ---- weights in registers (fp16, prescaled); bias via k=40 channel ----
  f16x8 whh[4][2], wih[4][2];
#pragma unroll
  for (int g = 0; g < 4; ++g) {
    const float s = gsc[g];
    const float* wr = w_hh + (size_t)(g * 64 + n) * 64;
#pragma unroll
    for (int kc = 0; kc < 2; ++kc) {
      float4 v0 = *(const float4*)(wr + kc * 32 + g16 * 8);
      float4 v1 = *(const float4*)(wr + kc * 32 + g16 * 8 + 4);
      v0.x *= s; v0.y *= s; v0.z *= s; v0.w *= s;
      v1.x *= s; v1.y *= s; v1.z *= s; v1.w *= s;
      whh[g][kc] = cvt8h(v0, v1);
    }
    const float* wi = w_ih + (size_t)(g * 64 + n) * IN_DIM;
    {
      float4 v0 = *(const float4*)(wi + g16 * 8);
      float4 v1 = *(const float4*)(wi + g16 * 8 + 4);
      v0.x *= s; v0.y *= s; v0.z *= s; v0.w *= s;
      v1.x *= s; v1.y *= s; v1.z *= s; v1.w *= s;
      wih[g][0] = cvt8h(v0, v1);
    }
    {
      float4 u0 = make_float4(0, 0, 0, 0), u1 = make_float4(0, 0, 0, 0);
      if (g16 == 0) {
        u0 = *(const float4*)(wi + 32);
        u1 = *(const float4*)(wi + 36);
        u0.x *= s; u0.y *= s; u0.z *= s; u0.w *= s;
        u1.x *= s; u1.y *= s; u1.z *= s; u1.w *= s;
      } else if (g16 == 1) {
        u0.x = (b_ih[g * 64 + n] + b_hh[g * 64 + n]) * s;   // k=40 bias row
      }
      wih[g][1] = cvt8h(u0, u1);
    }
  }
  __syncthreads();

  // A-row -> (slot, toff) mapping; x bases per group
  const int toff = (c15 >> 1) & 1;
  const int sx   = 2 * (c15 >> 2) + (c15 & 1);
  const float* xbA = x + (size_t)(b0 + sx) * T_STEPS * IN_DIM;
  const float* xbB = x + (size_t)(b0 + 8 + sx) * T_STEPS * IN_DIM;

  // LDS indices (R13-proven swizzle)
  const int akey  = (c15 >> 2) << 4;
  const int ridx0 = c15 * 64 + ((8 * g16) ^ akey);
  const int ridx1 = c15 * 64 + ((32 + 8 * g16) ^ akey);
  const int widx0 = (4 * g16) * 64 + (n ^ (g16 << 4));        // toff0 row, slot 2g16
  const int widx1 = (4 * g16 + 1) * 64 + (n ^ (g16 << 4));    // toff0 row, slot 2g16+1

  // x f32 prefetch regs (pair 0: lane time = toff)
  float4 pA0 = *(const float4*)(xbA + toff * IN_DIM + g16 * 8);
  float4 pA1 = *(const float4*)(xbA + toff * IN_DIM + g16 * 8 + 4);
  float4 qA0 = make_float4(0, 0, 0, 0), qA1 = make_float4(0, 0, 0, 0);
  float4 pB0 = *(const float4*)(xbB + toff * IN_DIM + g16 * 8);
  float4 pB1 = *(const float4*)(xbB + toff * IN_DIM + g16 * 8 + 4);
  float4 qB0 = make_float4(0, 0, 0, 0), qB1 = make_float4(0, 0, 0, 0);
  if (g16 == 0) {
    qA0 = *(const float4*)(xbA + toff * IN_DIM + 32);
    qA1 = *(const float4*)(xbA + toff * IN_DIM + 36);
    qB0 = *(const float4*)(xbB + toff * IN_DIM + 32);
    qB1 = *(const float4*)(xbB + toff * IN_DIM + 36);
  }
  f16x8 xf1c = {};
  if (g16 == 1) xf1c[0] = (_Float16)1.0f;   // k=40 bias multiplier

  f32x4 zA[4], zB[4];
  float ccA0 = 0.f, ccA1 = 0.f, ccB0 = 0.f, ccB1 = 0.f;
  float aclA0 = 0.f, aclA1 = 0.f, aclB0 = 0.f, aclB1 = 0.f;

  for (int p = 0; p < 151; ++p) {
    const int t0 = 2 * p;
    // ================= EVEN step t0: volley + rec, act toff0 =================
    {
      f16x8 aA0 = *(const f16x8*)(hA + ridx0);        // rb = 0
      f16x8 aA1 = *(const f16x8*)(hA + ridx1);
      f16x8 aB0 = *(const f16x8*)(hB + ridx0);
      f16x8 aB1 = *(const f16x8*)(hB + ridx1);

      const f16x8 xA0 = cvt8h(pA0, pA1);
      const f16x8 xA1 = (g16 == 0) ? cvt8h(qA0, qA1) : xf1c;
      const f16x8 xB0 = cvt8h(pB0, pB1);
      const f16x8 xB1 = (g16 == 0) ? cvt8h(qB0, qB1) : xf1c;
#pragma unroll
      for (int g = 0; g < 4; ++g) {
        f32x4 zz = {0.f, 0.f, 0.f, 0.f};
        zz = MFMA16(xA0, wih[g][0], zz);
        zA[g] = MFMA16(xA1, wih[g][1], zz);
      }
#pragma unroll
      for (int g = 0; g < 4; ++g) {
        zA[g] = MFMA16(aA0, whh[g][0], zA[g]);
        zA[g] = MFMA16(aA1, whh[g][1], zA[g]);
      }
#pragma unroll
      for (int g = 0; g < 4; ++g) {
        f32x4 zz = {0.f, 0.f, 0.f, 0.f};
        zz = MFMA16(xB0, wih[g][0], zz);
        zB[g] = MFMA16(xB1, wih[g][1], zz);
      }
#pragma unroll
      for (int g = 0; g < 4; ++g) {
        zB[g] = MFMA16(aB0, whh[g][0], zB[g]);
        zB[g] = MFMA16(aB1, whh[g][1], zB[g]);
      }

      // prefetch x for pair t0+2 (clamped; stays in flight)
      {
        const int tq = t0 + 2 + toff;
        const int tm = (tq <= T_STEPS - 1) ? tq : T_STEPS - 1;
        pA0 = *(const float4*)(xbA + (size_t)tm * IN_DIM + g16 * 8);
        pA1 = *(const float4*)(xbA + (size_t)tm * IN_DIM + g16 * 8 + 4);
        pB0 = *(const float4*)(xbB + (size_t)tm * IN_DIM + g16 * 8);
        pB1 = *(const float4*)(xbB + (size_t)tm * IN_DIM + g16 * 8 + 4);
        if (g16 == 0) {
          qA0 = *(const float4*)(xbA + (size_t)tm * IN_DIM + 32);
          qA1 = *(const float4*)(xbA + (size_t)tm * IN_DIM + 36);
          qB0 = *(const float4*)(xbB + (size_t)tm * IN_DIM + 32);
          qB1 = *(const float4*)(xbB + (size_t)tm * IN_DIM + 36);
        }
      }

      // merged act region: 8 independent chains (A0,A1,B0,B1 x nothing else)
      const float wc = wclf[t0 * 64 + n];
      {
        const float h = lstm_act(zA[0][0], zA[1][0], zA[2][0], zA[3][0], ccA0);
        aclA0 += h * wc;
        u16cv cv; cv.hf = (_Float16)h; hA[1024 + widx0] = cv.u;
      }
      {
        const float h = lstm_act(zA[0][1], zA[1][1], zA[2][1], zA[3][1], ccA1);
        aclA1 += h * wc;
        u16cv cv; cv.hf = (_Float16)h; hA[1024 + widx1] = cv.u;
      }
      {
        const float h = lstm_act(zB[0][0], zB[1][0], zB[2][0], zB[3][0], ccB0);
        aclB0 += h * wc;
        u16cv cv; cv.hf = (_Float16)h; hB[1024 + widx0] = cv.u;
      }
      {
        const float h = lstm_act(zB[0][1], zB[1][1], zB[2][1], zB[3][1], ccB1);
        aclB1 += h * wc;
        u16cv cv; cv.hf = (_Float16)h; hB[1024 + widx1] = cv.u;
      }
      if (p == 150) break;   // t = 300 done (uniform across grid)
      asm volatile("s_waitcnt lgkmcnt(0)\n\ts_barrier" ::: "memory");
    }
    // ================= ODD step t0+1: shuffle + rec, act ====================
    {
      f16x8 aA0 = *(const f16x8*)(hA + 1024 + ridx0);   // rb = 1
      f16x8 aA1 = *(const f16x8*)(hA + 1024 + ridx1);
      f16x8 aB0 = *(const f16x8*)(hB + 1024 + ridx0);
      f16x8 aB1 = *(const f16x8*)(hB + 1024 + ridx1);

      f32x4 sA[4], sB[4];
#pragma unroll
      for (int g = 0; g < 4; ++g) {
        sA[g] = __builtin_shufflevector(zA[g], zA[g], 2, 3, 2, 3);
        sA[g] = MFMA16(aA0, whh[g][0], sA[g]);
        sA[g] = MFMA16(aA1, whh[g][1], sA[g]);
      }
#pragma unroll
      for (int g = 0; g < 4; ++g) {
        sB[g] = __builtin_shufflevector(zB[g], zB[g], 2, 3, 2, 3);
        sB[g] = MFMA16(aB0, whh[g][0], sB[g]);
        sB[g] = MFMA16(aB1, whh[g][1], sB[g]);
      }

      const float wc = wclf[(t0 + 1) * 64 + n];
      {
        const float h = lstm_act(sA[0][0], sA[1][0], sA[2][0], sA[3][0], ccA0);
        aclA0 += h * wc;
        u16cv cv; cv.hf = (_Float16)h; hA[widx0] = cv.u;
      }
      {
        const float h = lstm_act(sA[0][1], sA[1][1], sA[2][1], sA[3][1], ccA1);
        aclA1 += h * wc;
        u16cv cv; cv.hf = (_Float16)h; hA[widx1] = cv.u;
      }
      {
        const float h = lstm_act(sB[0][0], sB[1][0], sB[2][0], sB[3][0], ccB0);
        aclB0 += h * wc;
        u16cv cv; cv.hf = (_Float16)h; hB[widx0] = cv.u;
      }
      {
        const float h = lstm_act(sB[0][1], sB[1][1], sB[2][1], sB[3][1], ccB1);
        aclB1 += h * wc;
        u16cv cv; cv.hf = (_Float16)h; hB[widx1] = cv.u;
      }
      asm volatile("s_waitcnt lgkmcnt(0)\n\ts_barrier" ::: "memory");
    }
  }

  // ---- epilogue: reduce over the 16 r15 lanes, then across waves ----
#pragma unroll
  for (int m = 1; m <= 8; m <<= 1) {
    aclA0 += __shfl_xor(aclA0, m);
    aclA1 += __shfl_xor(aclA1, m);
    aclB0 += __shfl_xor(aclB0, m);
    aclB1 += __shfl_xor(aclB1, m);
  }
  if (c15 == 0) {
    red[w * 16 + 2 * g16]         = aclA0;
    red[w * 16 + 2 * g16 + 1]     = aclA1;
    red[w * 16 + 8 + 2 * g16]     = aclB0;
    red[w * 16 + 8 + 2 * g16 + 1] = aclB1;
  }
  __syncthreads();
  if (tid < 16)
    out[b0 + tid] = b_clf[0] + red[tid] + red[16 + tid] + red[32 + tid] + red[48 + tid];
}

extern "C" void kernel_launch(void* const* d_in, const int* in_sizes, int n_in,
                              void* d_out, int out_size, void* d_ws, size_t ws_size,
                              hipStream_t stream) {
  const float* x     = (const float*)d_in[0];
  const float* w_ih  = (const float*)d_in[1];
  const float* w_hh  = (const float*)d_in[2];
  const float* b_ih  = (const float*)d_in[3];
  const float* b_hh  = (const float*)d_in[4];
  const float* w_clf = (const float*)d_in[5];
  const float* b_clf = (const float*)d_in[6];
  float* out = (float*)d_out;

  const size_t shmem = 77056 + 4096 + 4096 + 256;   // ~83.5 KB dynamic LDS
  (void)hipFuncSetAttribute((const void*)lstm_dg,
                            hipFuncAttributeMaxDynamicSharedMemorySize, (int)shmem);
  lstm_dg<<<256, 256, shmem, stream>>>(x, w_ih, w_hh, b_ih, b_hh, w_clf, b_clf, out);
}